// Round 4
// baseline (34626.059 us; speedup 1.0000x reference)
//
#include <hip/hip_runtime.h>
#include <hip/hip_bf16.h>
#include <cstddef>

typedef unsigned short u16;
typedef __attribute__((ext_vector_type(8))) short s8;   // 8 bf16 = 4 VGPRs
typedef __attribute__((ext_vector_type(4))) float f4;   // MFMA acc

constexpr int kB = 64, kT = 256, kD = 128, kH = 1024, kL = 5, kC = 10, kG = 4096;
constexpr int BH = kB * kH;
constexpr size_t WLA_ELEMS = (size_t)256 * 8 * 16384;   // 67 MB of u16
constexpr size_t WLB_ELEMS = (size_t)256 * 8 * 2560;    // 10.5 MB
constexpr size_t H_ELEMS = (size_t)kL * 2 * BH;

__device__ __forceinline__ float sigf(float x) { return 1.f / (1.f + __expf(-x)); }
__device__ __forceinline__ float tanh_s(float x) {
  float ax = fabsf(x);
  float e = __expf(-2.f * ax);
  float r = (1.f - e) / (1.f + e);
  return copysignf(r, x);
}
__device__ __forceinline__ void split_bf16(float v, short& hi, short& lo) {
  __hip_bfloat16 h = __float2bfloat16(v);
  hi = __builtin_bit_cast(short, h);
  float fh = __bfloat162float(h);
  __hip_bfloat16 l = __float2bfloat16(v - fh);
  lo = __builtin_bit_cast(short, l);
}
__device__ __forceinline__ short hi_bf16(float v) {
  __hip_bfloat16 h = __float2bfloat16(v);
  return __builtin_bit_cast(short, h);
}
__device__ __forceinline__ float bf2f(u16 v) {
  unsigned u = ((unsigned)v) << 16;
  return __builtin_bit_cast(float, u);
}

// ---- prep: split weights, write LO parts in per-(block,wave) fragment order ----
__global__ void __launch_bounds__(512) split_wl(const float* __restrict__ Wx0,
                                                const float* __restrict__ Wxs,
                                                const float* __restrict__ Whs,
                                                u16* __restrict__ wlA,
                                                u16* __restrict__ wlB) {
  const int g = blockIdx.x, tid = threadIdx.x;
  const int wv = tid >> 6, lane = tid & 63, quad = lane >> 4, r = lane & 15;
  const int lA = (g >> 6) + 1, jb = g & 63, kq = wv & 3, ch = wv >> 2;
  const float* WxA = Wxs + (size_t)(lA - 1) * kH * kG;
  const float* WhA = Whs + (size_t)lA * kH * kG;

  u16* dA = wlA + (size_t)(g * 8 + wv) * 16384;
  for (int p = 0; p < 16; ++p) {
    int kc = 4 * p + kq;
    const float* W = (kc < 32) ? WxA : WhA;
    int krow0 = (kc & 31) * 32 + quad * 8;
    for (int ntl = 0; ntl < 2; ++ntl) {
      int col = (2 * ch + ntl) * kH + jb * 16 + r;
      s8 l8;
      for (int j = 0; j < 8; ++j) {
        float w = W[(size_t)(krow0 + j) * kG + col];
        short hh, ll;
        split_bf16(w, hh, ll);
        l8[j] = ll;
      }
      *(s8*)(dA + (size_t)((p * 2 + ntl) * 64 + lane) * 8) = l8;
    }
  }

  u16* dB = wlB + (size_t)(g * 8 + wv) * 2560;
  int colB = (r >> 2) * kH + g * 4 + (r & 3);
  for (int j2 = 0; j2 < 4; ++j2) {
    int kb = (wv & 3) + 4 * (2 * j2 + (wv >> 2));
    int krow0 = kb * 32 + quad * 8;
    s8 l8;
    for (int j = 0; j < 8; ++j) {
      float w = Whs[(size_t)(krow0 + j) * kG + colB];
      short hh, ll;
      split_bf16(w, hh, ll);
      l8[j] = ll;
    }
    *(s8*)(dB + (size_t)(j2 * 64 + lane) * 8) = l8;
  }
  {
    int krow0 = (wv & 3) * 32 + quad * 8;
    s8 l8;
    for (int j = 0; j < 8; ++j) {
      float w = Wx0[(size_t)(krow0 + j) * kG + colB];
      short hh, ll;
      split_bf16(w, hh, ll);
      l8[j] = ll;
    }
    *(s8*)(dB + (size_t)(4 * 64 + lane) * 8) = l8;
  }
}

// Two-level grid barrier: 8 padded counters, monotonic targets (no reset).
__device__ __forceinline__ void grid_barrier(unsigned* bar, int g, int tid,
                                             unsigned target) {
  __threadfence();
  __syncthreads();
  if (tid == 0) {
    __hip_atomic_fetch_add(&bar[(g & 7) * 32], 1u, __ATOMIC_RELEASE,
                           __HIP_MEMORY_SCOPE_AGENT);
    unsigned sum;
    do {
      sum = 0;
#pragma unroll
      for (int i = 0; i < 8; ++i)
        sum += __hip_atomic_load(&bar[i * 32], __ATOMIC_RELAXED,
                                 __HIP_MEMORY_SCOPE_AGENT);
    } while (sum < target);
    (void)__hip_atomic_load(&bar[0], __ATOMIC_ACQUIRE, __HIP_MEMORY_SCOPE_AGENT);
  }
  __syncthreads();
}

// ---- main persistent kernel ----
__global__ void __launch_bounds__(512, 2) lstm_persist(
    const float* __restrict__ x, const float* __restrict__ Wx0,
    const float* __restrict__ Wxs, const float* __restrict__ Whs,
    const float* __restrict__ bs, const float* __restrict__ W_head,
    const float* __restrict__ b_head, float* __restrict__ out,
    u16* __restrict__ hhi, u16* __restrict__ hlo,
    const u16* __restrict__ wlA, const u16* __restrict__ wlB,
    unsigned* __restrict__ bar) {
  __shared__ s8 wlds[8 * 8 * 2 * 64];  // 128 KB: Wx-lo frags, per wave p=0..7
  __shared__ float zA[64 * 66];
  __shared__ float zB[64 * 18];

  const int tid = threadIdx.x;
  const int wv = tid >> 6, lane = tid & 63, quad = lane >> 4, r = lane & 15;
  const int ch = wv >> 2, kq = wv & 3;
  const int g = blockIdx.x;
  const int lA = (g >> 6) + 1;
  const int jb = g & 63;
  const int ub = g * 4;

  const float* __restrict__ WxA = Wxs + (size_t)(lA - 1) * kH * kG;
  const float* __restrict__ WhA = Whs + (size_t)lA * kH * kG;

  // ---- one-time: HI weight fragments into registers (AGPR-backed) ----
  s8 wA[16][2];  // 128 regs
#pragma unroll
  for (int p = 0; p < 16; ++p) {
    int kc = 4 * p + kq;
    const float* W = (kc < 32) ? WxA : WhA;
    int krow0 = (kc & 31) * 32 + quad * 8;
#pragma unroll
    for (int ntl = 0; ntl < 2; ++ntl) {
      int col = (2 * ch + ntl) * kH + jb * 16 + r;
      s8 h8;
#pragma unroll
      for (int j = 0; j < 8; ++j) h8[j] = hi_bf16(W[(size_t)(krow0 + j) * kG + col]);
      wA[p][ntl] = h8;
    }
  }
  s8 wBh[4], wBx;
  {
    int colB = (r >> 2) * kH + ub + (r & 3);
#pragma unroll
    for (int j2 = 0; j2 < 4; ++j2) {
      int kb = (wv & 3) + 4 * (2 * j2 + (wv >> 2));
      int krow0 = kb * 32 + quad * 8;
      s8 h8;
#pragma unroll
      for (int j = 0; j < 8; ++j) h8[j] = hi_bf16(Whs[(size_t)(krow0 + j) * kG + colB]);
      wBh[j2] = h8;
    }
    int krow0 = (wv & 3) * 32 + quad * 8;
    s8 h8;
#pragma unroll
    for (int j = 0; j < 8; ++j) h8[j] = hi_bf16(Wx0[(size_t)(krow0 + j) * kG + colB]);
    wBx = h8;
  }

  const u16* wlAs = wlA + (size_t)(g * 8 + wv) * 16384;
  const u16* wlBs = wlB + (size_t)(g * 8 + wv) * 2560;

  // ---- one-time: Wx-lo fragments (p=0..7) into LDS ----
#pragma unroll
  for (int p = 0; p < 8; ++p)
#pragma unroll
    for (int ntl = 0; ntl < 2; ++ntl)
      wlds[((wv * 8 + p) * 2 + ntl) * 64 + lane] =
          *(const s8*)(wlAs + (size_t)((p * 2 + ntl) * 64 + lane) * 8);

  float bA[4], bB[4];
  {
    int u = tid & 15;
#pragma unroll
    for (int g4 = 0; g4 < 4; ++g4) bA[g4] = bs[(size_t)lA * kG + g4 * kH + jb * 16 + u];
    int u2 = tid & 3;
#pragma unroll
    for (int g4 = 0; g4 < 4; ++g4) bB[g4] = bs[(size_t)g4 * kH + ub + u2];
  }
  float cA0 = 0.f, cA1 = 0.f, cB0 = 0.f;
  const s8 zf = {0, 0, 0, 0, 0, 0, 0, 0};
  const f4 zero4 = {0.f, 0.f, 0.f, 0.f};
  const int kbase = kq * 32 + quad * 8;

  __syncthreads();

  // ---- wavefront loop ----
  for (int s = 0; s < kT + kL - 1; ++s) {
    const int tA = s - lA;
    const int tB = s;

    for (int i = tid; i < 64 * 66; i += 512) zA[i] = 0.f;
    for (int i = tid; i < 64 * 18; i += 512) zB[i] = 0.f;
    __syncthreads();

    // ---- task A: 64 cols of layer lA; p-sequence [8..15, 0..7] ----
    if (tA >= 0 && tA < kT) {
      const u16* IH = hhi + (size_t)((lA - 1) * 2 + (tA & 1)) * BH;
      const u16* IL = hlo + (size_t)((lA - 1) * 2 + (tA & 1)) * BH;
      const u16* RH = hhi + (size_t)(lA * 2 + ((tA - 1) & 1)) * BH;
      const u16* RL = hlo + (size_t)(lA * 2 + ((tA - 1) & 1)) * BH;
      const bool zz = (tA == 0);
      f4 accA[2][4];
#pragma unroll
      for (int a = 0; a < 2; ++a)
#pragma unroll
        for (int b = 0; b < 4; ++b) accA[a][b] = zero4;

      s8 wlq[2][2], ah_n[4];
      // prologue: stream wl(8),wl(9); prefetch ah(8)
      wlq[0][0] = *(const s8*)(wlAs + (size_t)((16 + 0) * 64 + lane) * 8);
      wlq[0][1] = *(const s8*)(wlAs + (size_t)((16 + 1) * 64 + lane) * 8);
      wlq[1][0] = *(const s8*)(wlAs + (size_t)((18 + 0) * 64 + lane) * 8);
      wlq[1][1] = *(const s8*)(wlAs + (size_t)((18 + 1) * 64 + lane) * 8);
#pragma unroll
      for (int mt = 0; mt < 4; ++mt)
        ah_n[mt] = *(const s8*)(RH + (size_t)(mt * 16 + r) * kH + kbase);

#pragma unroll
      for (int idx = 0; idx < 16; ++idx) {
        const int p = (idx < 8) ? 8 + idx : idx - 8;
        const bool curR = (p >= 8);
        s8 ah_c[4];
#pragma unroll
        for (int mt = 0; mt < 4; ++mt) ah_c[mt] = (curR && zz) ? zf : ah_n[mt];
        // prefetch next ah
        if (idx < 15) {
          const int pn = (idx < 7) ? 9 + idx : idx - 7;
          const u16* SH = (pn >= 8) ? RH : IH;
#pragma unroll
          for (int mt = 0; mt < 4; ++mt)
            ah_n[mt] = *(const s8*)(SH + (size_t)(mt * 16 + r) * kH +
                                    (pn & 7) * 128 + kbase);
        }
        // wl for current p
        s8 wl0, wl1;
        if (idx < 8) {
          wl0 = wlq[idx & 1][0];
          wl1 = wlq[idx & 1][1];
          if (idx < 6) {
            const int pw = 10 + idx;
            wlq[idx & 1][0] = *(const s8*)(wlAs + (size_t)((pw * 2 + 0) * 64 + lane) * 8);
            wlq[idx & 1][1] = *(const s8*)(wlAs + (size_t)((pw * 2 + 1) * 64 + lane) * 8);
          }
        } else {
          wl0 = wlds[((wv * 8 + p) * 2 + 0) * 64 + lane];
          wl1 = wlds[((wv * 8 + p) * 2 + 1) * 64 + lane];
        }
        // al at use
        const u16* SL = curR ? RL : IL;
        s8 al_c[4];
#pragma unroll
        for (int mt = 0; mt < 4; ++mt) {
          s8 v = *(const s8*)(SL + (size_t)(mt * 16 + r) * kH + (p & 7) * 128 + kbase);
          al_c[mt] = (curR && zz) ? zf : v;
        }
#pragma unroll
        for (int mt = 0; mt < 4; ++mt) {
          f4 a0 = accA[0][mt], a1 = accA[1][mt];
          a0 = __builtin_amdgcn_mfma_f32_16x16x32_bf16(ah_c[mt], wA[p][0], a0, 0, 0, 0);
          a0 = __builtin_amdgcn_mfma_f32_16x16x32_bf16(al_c[mt], wA[p][0], a0, 0, 0, 0);
          a0 = __builtin_amdgcn_mfma_f32_16x16x32_bf16(ah_c[mt], wl0, a0, 0, 0, 0);
          a1 = __builtin_amdgcn_mfma_f32_16x16x32_bf16(ah_c[mt], wA[p][1], a1, 0, 0, 0);
          a1 = __builtin_amdgcn_mfma_f32_16x16x32_bf16(al_c[mt], wA[p][1], a1, 0, 0, 0);
          a1 = __builtin_amdgcn_mfma_f32_16x16x32_bf16(ah_c[mt], wl1, a1, 0, 0, 0);
          accA[0][mt] = a0;
          accA[1][mt] = a1;
        }
      }
#pragma unroll
      for (int ntl = 0; ntl < 2; ++ntl)
#pragma unroll
        for (int mt = 0; mt < 4; ++mt)
#pragma unroll
          for (int v = 0; v < 4; ++v)
            atomicAdd(&zA[(mt * 16 + quad * 4 + v) * 66 + (2 * ch + ntl) * 16 + r],
                      accA[ntl][mt][v]);
    }

    // ---- task B: 4 units of layer 0 ----
    if (tB < kT) {
      const u16* H0H = hhi + (size_t)((tB - 1) & 1) * BH;
      const u16* H0L = hlo + (size_t)((tB - 1) & 1) * BH;
      const bool z0 = (tB == 0);
      f4 accB[4];
#pragma unroll
      for (int b = 0; b < 4; ++b) accB[b] = zero4;

      s8 wlb_n = *(const s8*)(wlBs + (size_t)(0 * 64 + lane) * 8);
      s8 ahb_n[4];
      {
        const int kb0 = (wv & 3) + 4 * (wv >> 2);
        const int k00 = kb0 * 32 + quad * 8;
#pragma unroll
        for (int mt = 0; mt < 4; ++mt)
          ahb_n[mt] = *(const s8*)(H0H + (size_t)(mt * 16 + r) * kH + k00);
      }
#pragma unroll
      for (int j2 = 0; j2 < 4; ++j2) {
        const int kb = (wv & 3) + 4 * (2 * j2 + (wv >> 2));
        const int k0c = kb * 32 + quad * 8;
        s8 wlv = wlb_n;
        s8 ahb_c[4];
#pragma unroll
        for (int mt = 0; mt < 4; ++mt) ahb_c[mt] = z0 ? zf : ahb_n[mt];
        if (j2 < 3) {
          wlb_n = *(const s8*)(wlBs + (size_t)((j2 + 1) * 64 + lane) * 8);
          const int kbn = (wv & 3) + 4 * (2 * (j2 + 1) + (wv >> 2));
          const int k0n = kbn * 32 + quad * 8;
#pragma unroll
          for (int mt = 0; mt < 4; ++mt)
            ahb_n[mt] = *(const s8*)(H0H + (size_t)(mt * 16 + r) * kH + k0n);
        }
        s8 alb[4];
#pragma unroll
        for (int mt = 0; mt < 4; ++mt) {
          s8 v = *(const s8*)(H0L + (size_t)(mt * 16 + r) * kH + k0c);
          alb[mt] = z0 ? zf : v;
        }
#pragma unroll
        for (int mt = 0; mt < 4; ++mt) {
          f4 a = accB[mt];
          a = __builtin_amdgcn_mfma_f32_16x16x32_bf16(ahb_c[mt], wBh[j2], a, 0, 0, 0);
          a = __builtin_amdgcn_mfma_f32_16x16x32_bf16(alb[mt], wBh[j2], a, 0, 0, 0);
          a = __builtin_amdgcn_mfma_f32_16x16x32_bf16(ahb_c[mt], wlv, a, 0, 0, 0);
          accB[mt] = a;
        }
      }
      if (wv >= 4) {
        const int c = wv - 4;
        s8 wlx = *(const s8*)(wlBs + (size_t)(4 * 64 + lane) * 8);
#pragma unroll
        for (int mt = 0; mt < 4; ++mt) {
          const float* sx =
              x + (size_t)(mt * 16 + r) * kT * kD + (size_t)tB * kD + c * 32 + quad * 8;
          float4 v0 = *(const float4*)sx;
          float4 v1 = *(const float4*)(sx + 4);
          float vv[8] = {v0.x, v0.y, v0.z, v0.w, v1.x, v1.y, v1.z, v1.w};
          s8 xh, xl;
#pragma unroll
          for (int e = 0; e < 8; ++e) {
            short hh, ll;
            split_bf16(vv[e], hh, ll);
            xh[e] = hh;
            xl[e] = ll;
          }
          f4 a = accB[mt];
          a = __builtin_amdgcn_mfma_f32_16x16x32_bf16(xh, wBx, a, 0, 0, 0);
          a = __builtin_amdgcn_mfma_f32_16x16x32_bf16(xl, wBx, a, 0, 0, 0);
          a = __builtin_amdgcn_mfma_f32_16x16x32_bf16(xh, wlx, a, 0, 0, 0);
          accB[mt] = a;
        }
      }
#pragma unroll
      for (int mt = 0; mt < 4; ++mt)
#pragma unroll
        for (int v = 0; v < 4; ++v)
          atomicAdd(&zB[(mt * 16 + quad * 4 + v) * 18 + r], accB[mt][v]);
    }

    __syncthreads();

    // ---- gates + h store ----
    if (tA >= 0 && tA < kT) {
      const int par = tA & 1;
      u16* HH = hhi + (size_t)(lA * 2 + par) * BH;
      u16* HL = hlo + (size_t)(lA * 2 + par) * BH;
#pragma unroll
      for (int rp = 0; rp < 2; ++rp) {
        int p2 = tid + 512 * rp;
        int b = p2 >> 4, u = p2 & 15;
        float zi = zA[b * 66 + u] + bA[0];
        float zfg = zA[b * 66 + 16 + u] + bA[1];
        float zg = zA[b * 66 + 32 + u] + bA[2];
        float zo = zA[b * 66 + 48 + u] + bA[3];
        float cp = (tA == 0) ? 0.f : (rp ? cA1 : cA0);
        float cn = sigf(zfg) * cp + sigf(zi) * tanh_s(zg);
        float hn = sigf(zo) * tanh_s(cn);
        if (rp) cA1 = cn; else cA0 = cn;
        short hh, ll;
        split_bf16(hn, hh, ll);
        size_t off = (size_t)b * kH + jb * 16 + u;
        HH[off] = (u16)hh;
        HL[off] = (u16)ll;
      }
    }
    if (tB < kT && tid < 256) {
      const int par = tB & 1;
      u16* HH = hhi + (size_t)par * BH;
      u16* HL = hlo + (size_t)par * BH;
      int b = tid >> 2, u = tid & 3;
      float zi = zB[b * 18 + u] + bB[0];
      float zfg = zB[b * 18 + 4 + u] + bB[1];
      float zg = zB[b * 18 + 8 + u] + bB[2];
      float zo = zB[b * 18 + 12 + u] + bB[3];
      float cp = (tB == 0) ? 0.f : cB0;
      float cn = sigf(zfg) * cp + sigf(zi) * tanh_s(zg);
      float hn = sigf(zo) * tanh_s(cn);
      cB0 = cn;
      short hh, ll;
      split_bf16(hn, hh, ll);
      size_t off = (size_t)b * kH + ub + u;
      HH[off] = (u16)hh;
      HL[off] = (u16)ll;
    }

    grid_barrier(bar, g, tid, 256u * (unsigned)(s + 1));
  }

  // ---- head ----
  if (g < 80) {
    int p = g * 8 + wv;
    int b = p / 10, cc = p - b * 10;
    const u16* HH = hhi + (size_t)(4 * 2 + 1) * BH + (size_t)b * kH;
    const u16* HL = hlo + (size_t)(4 * 2 + 1) * BH + (size_t)b * kH;
    float sum = 0.f;
    for (int j = lane; j < kH; j += 64)
      sum += (bf2f(HH[j]) + bf2f(HL[j])) * W_head[(size_t)j * kC + cc];
#pragma unroll
    for (int off = 32; off > 0; off >>= 1) sum += __shfl_down(sum, off, 64);
    if (lane == 0) out[p] = sum + b_head[cc];
  }
}

// Fallback weight-lo buffer, allocated at library load (NOT inside kernel_launch).
static u16* g_wl = nullptr;
__attribute__((constructor)) static void alloc_wl() {
  hipMalloc((void**)&g_wl, (WLA_ELEMS + WLB_ELEMS) * sizeof(u16));
}

extern "C" void kernel_launch(void* const* d_in, const int* in_sizes, int n_in,
                              void* d_out, int out_size, void* d_ws, size_t ws_size,
                              hipStream_t stream) {
  const float* x = (const float*)d_in[0];
  const float* Wx0 = (const float*)d_in[1];
  const float* Wxs = (const float*)d_in[2];
  const float* Whs = (const float*)d_in[3];
  const float* bs = (const float*)d_in[4];
  const float* W_head = (const float*)d_in[5];
  const float* b_head = (const float*)d_in[6];
  float* out = (float*)d_out;

  u16* hhi = (u16*)d_ws;
  u16* hlo = hhi + H_ELEMS;
  unsigned* bar = (unsigned*)(hlo + H_ELEMS);        // 1 KB barrier counters
  u16* ws_wl = (u16*)((char*)d_ws + 2 * H_ELEMS * sizeof(u16) + 1024);
  size_t need = 2 * H_ELEMS * sizeof(u16) + 1024 +
                (WLA_ELEMS + WLB_ELEMS) * sizeof(u16);
  u16 *wlA, *wlB;
  if (ws_size >= need) {
    wlA = ws_wl;
    wlB = wlA + WLA_ELEMS;
  } else {
    wlA = g_wl;
    wlB = g_wl + WLA_ELEMS;
  }

  hipMemsetAsync(bar, 0, 1024, stream);
  split_wl<<<256, 512, 0, stream>>>(Wx0, Wxs, Whs, wlA, wlB);

  void* args[] = {&x, &Wx0, &Wxs, &Whs, &bs, &W_head, &b_head,
                  &out, &hhi, &hlo, &wlA, &wlB, &bar};
  hipLaunchCooperativeKernel((void*)lstm_persist, dim3(256), dim3(512), args, 0,
                             stream);
}

// Round 5
// 27609.882 us; speedup vs baseline: 1.2541x; 1.2541x over previous
//
#include <hip/hip_runtime.h>
#include <hip/hip_cooperative_groups.h>
#include <hip/hip_bf16.h>
#include <cstddef>

namespace cg = cooperative_groups;

typedef unsigned short u16;
typedef __attribute__((ext_vector_type(8))) short s8;   // 8 bf16 = 4 VGPRs
typedef __attribute__((ext_vector_type(4))) float f4;   // MFMA acc

constexpr int kB = 64, kT = 256, kD = 128, kH = 1024, kL = 5, kC = 10, kG = 4096;
constexpr int BH = kB * kH;
constexpr size_t WLA_ELEMS = (size_t)256 * 8 * 16384;   // 67 MB of u16
constexpr size_t WLB_ELEMS = (size_t)256 * 8 * 2560;    // 10.5 MB
constexpr size_t H_ELEMS = (size_t)kL * 2 * BH;

// h activations are stored FRAGMENT-CONTIGUOUS: H2[k>>3][b][k&7] (u16), i.e.
// flat index ((k>>3)*64 + b)*8 + (k&7). A-fragment load for (k-chunk kk8, rows
// mt*16+r) = 16B at ((kk8*64 + mt*16 + r)*8): lanes r give 256B contiguous,
// quad strides 1KB -> 4 transactions/load instead of 16 (row-major was 2KB
// row stride = 16-line gather, which serialized the TA).

__device__ __forceinline__ float sigf(float x) { return 1.f / (1.f + __expf(-x)); }
__device__ __forceinline__ float tanh_s(float x) {
  float ax = fabsf(x);
  float e = __expf(-2.f * ax);
  float r = (1.f - e) / (1.f + e);
  return copysignf(r, x);
}
__device__ __forceinline__ void split_bf16(float v, short& hi, short& lo) {
  __hip_bfloat16 h = __float2bfloat16(v);
  hi = __builtin_bit_cast(short, h);
  float fh = __bfloat162float(h);
  __hip_bfloat16 l = __float2bfloat16(v - fh);
  lo = __builtin_bit_cast(short, l);
}
__device__ __forceinline__ short hi_bf16(float v) {
  __hip_bfloat16 h = __float2bfloat16(v);
  return __builtin_bit_cast(short, h);
}
__device__ __forceinline__ float bf2f(u16 v) {
  unsigned u = ((unsigned)v) << 16;
  return __builtin_bit_cast(float, u);
}

// ---- prep: split weights, write LO parts in per-(block,wave) fragment order ----
__global__ void __launch_bounds__(512) split_wl(const float* __restrict__ Wx0,
                                                const float* __restrict__ Wxs,
                                                const float* __restrict__ Whs,
                                                u16* __restrict__ wlA,
                                                u16* __restrict__ wlB) {
  const int g = blockIdx.x, tid = threadIdx.x;
  const int wv = tid >> 6, lane = tid & 63, quad = lane >> 4, r = lane & 15;
  const int lA = (g >> 6) + 1, jb = g & 63, kq = wv & 3, ch = wv >> 2;
  const float* WxA = Wxs + (size_t)(lA - 1) * kH * kG;
  const float* WhA = Whs + (size_t)lA * kH * kG;

  u16* dA = wlA + (size_t)(g * 8 + wv) * 16384;
  for (int p = 0; p < 16; ++p) {
    int kc = 4 * p + kq;
    const float* W = (kc < 32) ? WxA : WhA;
    int krow0 = (kc & 31) * 32 + quad * 8;
    for (int ntl = 0; ntl < 2; ++ntl) {
      int col = (2 * ch + ntl) * kH + jb * 16 + r;
      s8 l8;
      for (int j = 0; j < 8; ++j) {
        float w = W[(size_t)(krow0 + j) * kG + col];
        short hh, ll;
        split_bf16(w, hh, ll);
        l8[j] = ll;
      }
      *(s8*)(dA + (size_t)((p * 2 + ntl) * 64 + lane) * 8) = l8;
    }
  }

  u16* dB = wlB + (size_t)(g * 8 + wv) * 2560;
  int colB = (r >> 2) * kH + g * 4 + (r & 3);
  for (int j2 = 0; j2 < 4; ++j2) {
    int kb = (wv & 3) + 4 * (2 * j2 + (wv >> 2));
    int krow0 = kb * 32 + quad * 8;
    s8 l8;
    for (int j = 0; j < 8; ++j) {
      float w = Whs[(size_t)(krow0 + j) * kG + colB];
      short hh, ll;
      split_bf16(w, hh, ll);
      l8[j] = ll;
    }
    *(s8*)(dB + (size_t)(j2 * 64 + lane) * 8) = l8;
  }
  {
    int krow0 = (wv & 3) * 32 + quad * 8;
    s8 l8;
    for (int j = 0; j < 8; ++j) {
      float w = Wx0[(size_t)(krow0 + j) * kG + colB];
      short hh, ll;
      split_bf16(w, hh, ll);
      l8[j] = ll;
    }
    *(s8*)(dB + (size_t)(4 * 64 + lane) * 8) = l8;
  }
}

// ---- main persistent kernel ----
__global__ void __launch_bounds__(512, 2) lstm_persist(
    const float* __restrict__ x, const float* __restrict__ Wx0,
    const float* __restrict__ Wxs, const float* __restrict__ Whs,
    const float* __restrict__ bs, const float* __restrict__ W_head,
    const float* __restrict__ b_head, float* __restrict__ out,
    u16* __restrict__ hhi, u16* __restrict__ hlo,
    const u16* __restrict__ wlA, const u16* __restrict__ wlB) {
  cg::grid_group grid = cg::this_grid();
  __shared__ s8 wlds[8 * 8 * 2 * 64];  // 128 KB: Wx-lo frags (p=0..7) per wave
  __shared__ float zA[64 * 66];
  __shared__ float zB[64 * 18];

  const int tid = threadIdx.x;
  const int wv = tid >> 6, lane = tid & 63, quad = lane >> 4, r = lane & 15;
  const int ch = wv >> 2, kq = wv & 3;
  const int g = blockIdx.x;
  const int lA = (g >> 6) + 1;
  const int jb = g & 63;
  const int ub = g * 4;

  const float* __restrict__ WxA = Wxs + (size_t)(lA - 1) * kH * kG;
  const float* __restrict__ WhA = Whs + (size_t)lA * kH * kG;

  // ---- one-time: HI weight fragments into registers (AGPR-backed) ----
  s8 wA[16][2];  // 128 regs
#pragma unroll
  for (int p = 0; p < 16; ++p) {
    int kc = 4 * p + kq;
    const float* W = (kc < 32) ? WxA : WhA;
    int krow0 = (kc & 31) * 32 + quad * 8;
#pragma unroll
    for (int ntl = 0; ntl < 2; ++ntl) {
      int col = (2 * ch + ntl) * kH + jb * 16 + r;
      s8 h8;
#pragma unroll
      for (int j = 0; j < 8; ++j) h8[j] = hi_bf16(W[(size_t)(krow0 + j) * kG + col]);
      wA[p][ntl] = h8;
    }
  }
  s8 wBh[4], wBx;
  {
    int colB = (r >> 2) * kH + ub + (r & 3);
#pragma unroll
    for (int j2 = 0; j2 < 4; ++j2) {
      int kb = (wv & 3) + 4 * (2 * j2 + (wv >> 2));
      int krow0 = kb * 32 + quad * 8;
      s8 h8;
#pragma unroll
      for (int j = 0; j < 8; ++j) h8[j] = hi_bf16(Whs[(size_t)(krow0 + j) * kG + colB]);
      wBh[j2] = h8;
    }
    int krow0 = (wv & 3) * 32 + quad * 8;
    s8 h8;
#pragma unroll
    for (int j = 0; j < 8; ++j) h8[j] = hi_bf16(Wx0[(size_t)(krow0 + j) * kG + colB]);
    wBx = h8;
  }

  const u16* wlAs = wlA + (size_t)(g * 8 + wv) * 16384;
  const u16* wlBs = wlB + (size_t)(g * 8 + wv) * 2560;

  // ---- one-time: Wx-lo fragments (p=0..7) into LDS ----
#pragma unroll
  for (int p = 0; p < 8; ++p)
#pragma unroll
    for (int ntl = 0; ntl < 2; ++ntl)
      wlds[((wv * 8 + p) * 2 + ntl) * 64 + lane] =
          *(const s8*)(wlAs + (size_t)((p * 2 + ntl) * 64 + lane) * 8);

  float bA[4], bB[4];
  {
    int u = tid & 15;
#pragma unroll
    for (int g4 = 0; g4 < 4; ++g4) bA[g4] = bs[(size_t)lA * kG + g4 * kH + jb * 16 + u];
    int u2 = tid & 3;
#pragma unroll
    for (int g4 = 0; g4 < 4; ++g4) bB[g4] = bs[(size_t)g4 * kH + ub + u2];
  }
  float cA0 = 0.f, cA1 = 0.f, cB0 = 0.f;
  const s8 zf = {0, 0, 0, 0, 0, 0, 0, 0};
  const f4 zero4 = {0.f, 0.f, 0.f, 0.f};
  const int fragbase = kq * 4 + quad;  // kk8 offset within a 16-group (128 k)

  __syncthreads();

  // ---- wavefront loop ----
  for (int s = 0; s < kT + kL - 1; ++s) {
    const int tA = s - lA;
    const int tB = s;

    for (int i = tid; i < 64 * 66; i += 512) zA[i] = 0.f;
    for (int i = tid; i < 64 * 18; i += 512) zB[i] = 0.f;
    __syncthreads();

    // ---- task A: 64 cols of layer lA; p=0..7 input (parked wl), 8..15 recurrent ----
    if (tA >= 0 && tA < kT) {
      const u16* IH = hhi + (size_t)((lA - 1) * 2 + (tA & 1)) * BH;
      const u16* IL = hlo + (size_t)((lA - 1) * 2 + (tA & 1)) * BH;
      const u16* RH = hhi + (size_t)(lA * 2 + ((tA - 1) & 1)) * BH;
      const u16* RL = hlo + (size_t)(lA * 2 + ((tA - 1) & 1)) * BH;
      const bool zz = (tA == 0);
      f4 accA[2][4];
#pragma unroll
      for (int a = 0; a < 2; ++a)
#pragma unroll
        for (int b = 0; b < 4; ++b) accA[a][b] = zero4;

      // prologue: start streaming wh-lo chunks p=8,9 NOW; they land while we
      // compute the parked half. Also prefetch ah for p=0.
      s8 wlq[2][2], ah_n[4];
      wlq[0][0] = *(const s8*)(wlAs + (size_t)((16 + 0) * 64 + lane) * 8);
      wlq[0][1] = *(const s8*)(wlAs + (size_t)((16 + 1) * 64 + lane) * 8);
      wlq[1][0] = *(const s8*)(wlAs + (size_t)((18 + 0) * 64 + lane) * 8);
      wlq[1][1] = *(const s8*)(wlAs + (size_t)((18 + 1) * 64 + lane) * 8);
#pragma unroll
      for (int mt = 0; mt < 4; ++mt)
        ah_n[mt] = *(const s8*)(IH + (size_t)(fragbase * 64 + mt * 16 + r) * 8);

#pragma unroll
      for (int p = 0; p < 16; ++p) {
        const bool curR = (p >= 8);
        s8 ah_c[4];
#pragma unroll
        for (int mt = 0; mt < 4; ++mt) ah_c[mt] = (curR && zz) ? zf : ah_n[mt];
        // prefetch next ah
        if (p < 15) {
          const int pn = p + 1;
          const u16* SH = (pn >= 8) ? RH : IH;
          const int kb8 = ((pn & 7) * 16 + fragbase) * 64;
#pragma unroll
          for (int mt = 0; mt < 4; ++mt)
            ah_n[mt] = *(const s8*)(SH + (size_t)(kb8 + mt * 16 + r) * 8);
        }
        // wl for current p
        s8 wl0, wl1;
        if (p < 8) {
          wl0 = wlds[((wv * 8 + p) * 2 + 0) * 64 + lane];
          wl1 = wlds[((wv * 8 + p) * 2 + 1) * 64 + lane];
        } else {
          wl0 = wlq[p & 1][0];
          wl1 = wlq[p & 1][1];
          if (p < 14) {
            const int pw = p + 2;
            wlq[p & 1][0] = *(const s8*)(wlAs + (size_t)((pw * 2 + 0) * 64 + lane) * 8);
            wlq[p & 1][1] = *(const s8*)(wlAs + (size_t)((pw * 2 + 1) * 64 + lane) * 8);
          }
        }
        // al at use
        const u16* SL = curR ? RL : IL;
        const int kb8c = ((p & 7) * 16 + fragbase) * 64;
        s8 al_c[4];
#pragma unroll
        for (int mt = 0; mt < 4; ++mt) {
          s8 v = *(const s8*)(SL + (size_t)(kb8c + mt * 16 + r) * 8);
          al_c[mt] = (curR && zz) ? zf : v;
        }
#pragma unroll
        for (int mt = 0; mt < 4; ++mt) {
          f4 a0 = accA[0][mt], a1 = accA[1][mt];
          a0 = __builtin_amdgcn_mfma_f32_16x16x32_bf16(ah_c[mt], wA[p][0], a0, 0, 0, 0);
          a0 = __builtin_amdgcn_mfma_f32_16x16x32_bf16(al_c[mt], wA[p][0], a0, 0, 0, 0);
          a0 = __builtin_amdgcn_mfma_f32_16x16x32_bf16(ah_c[mt], wl0, a0, 0, 0, 0);
          a1 = __builtin_amdgcn_mfma_f32_16x16x32_bf16(ah_c[mt], wA[p][1], a1, 0, 0, 0);
          a1 = __builtin_amdgcn_mfma_f32_16x16x32_bf16(al_c[mt], wA[p][1], a1, 0, 0, 0);
          a1 = __builtin_amdgcn_mfma_f32_16x16x32_bf16(ah_c[mt], wl1, a1, 0, 0, 0);
          accA[0][mt] = a0;
          accA[1][mt] = a1;
        }
      }
#pragma unroll
      for (int ntl = 0; ntl < 2; ++ntl)
#pragma unroll
        for (int mt = 0; mt < 4; ++mt)
#pragma unroll
          for (int v = 0; v < 4; ++v)
            atomicAdd(&zA[(mt * 16 + quad * 4 + v) * 66 + (2 * ch + ntl) * 16 + r],
                      accA[ntl][mt][v]);
    }

    // ---- task B: 4 units of layer 0 ----
    if (tB < kT) {
      const u16* H0H = hhi + (size_t)((tB - 1) & 1) * BH;
      const u16* H0L = hlo + (size_t)((tB - 1) & 1) * BH;
      const bool z0 = (tB == 0);
      f4 accB[4];
#pragma unroll
      for (int b = 0; b < 4; ++b) accB[b] = zero4;

      s8 wlb_n = *(const s8*)(wlBs + (size_t)(0 * 64 + lane) * 8);
      s8 ahb_n[4];
      {
        const int kb0 = (wv & 3) + 4 * (wv >> 2);
        const int kb8 = (kb0 * 4 + quad) * 64;
#pragma unroll
        for (int mt = 0; mt < 4; ++mt)
          ahb_n[mt] = *(const s8*)(H0H + (size_t)(kb8 + mt * 16 + r) * 8);
      }
#pragma unroll
      for (int j2 = 0; j2 < 4; ++j2) {
        const int kb = (wv & 3) + 4 * (2 * j2 + (wv >> 2));
        const int kb8c = (kb * 4 + quad) * 64;
        s8 wlv = wlb_n;
        s8 ahb_c[4];
#pragma unroll
        for (int mt = 0; mt < 4; ++mt) ahb_c[mt] = z0 ? zf : ahb_n[mt];
        if (j2 < 3) {
          wlb_n = *(const s8*)(wlBs + (size_t)((j2 + 1) * 64 + lane) * 8);
          const int kbn = (wv & 3) + 4 * (2 * (j2 + 1) + (wv >> 2));
          const int kb8n = (kbn * 4 + quad) * 64;
#pragma unroll
          for (int mt = 0; mt < 4; ++mt)
            ahb_n[mt] = *(const s8*)(H0H + (size_t)(kb8n + mt * 16 + r) * 8);
        }
        s8 alb[4];
#pragma unroll
        for (int mt = 0; mt < 4; ++mt) {
          s8 v = *(const s8*)(H0L + (size_t)(kb8c + mt * 16 + r) * 8);
          alb[mt] = z0 ? zf : v;
        }
#pragma unroll
        for (int mt = 0; mt < 4; ++mt) {
          f4 a = accB[mt];
          a = __builtin_amdgcn_mfma_f32_16x16x32_bf16(ahb_c[mt], wBh[j2], a, 0, 0, 0);
          a = __builtin_amdgcn_mfma_f32_16x16x32_bf16(alb[mt], wBh[j2], a, 0, 0, 0);
          a = __builtin_amdgcn_mfma_f32_16x16x32_bf16(ahb_c[mt], wlv, a, 0, 0, 0);
          accB[mt] = a;
        }
      }
      if (wv >= 4) {
        const int c = wv - 4;
        s8 wlx = *(const s8*)(wlBs + (size_t)(4 * 64 + lane) * 8);
#pragma unroll
        for (int mt = 0; mt < 4; ++mt) {
          const float* sx =
              x + (size_t)(mt * 16 + r) * kT * kD + (size_t)tB * kD + c * 32 + quad * 8;
          float4 v0 = *(const float4*)sx;
          float4 v1 = *(const float4*)(sx + 4);
          float vv[8] = {v0.x, v0.y, v0.z, v0.w, v1.x, v1.y, v1.z, v1.w};
          s8 xh, xl;
#pragma unroll
          for (int e = 0; e < 8; ++e) {
            short hh, ll;
            split_bf16(vv[e], hh, ll);
            xh[e] = hh;
            xl[e] = ll;
          }
          f4 a = accB[mt];
          a = __builtin_amdgcn_mfma_f32_16x16x32_bf16(xh, wBx, a, 0, 0, 0);
          a = __builtin_amdgcn_mfma_f32_16x16x32_bf16(xl, wBx, a, 0, 0, 0);
          a = __builtin_amdgcn_mfma_f32_16x16x32_bf16(xh, wlx, a, 0, 0, 0);
          accB[mt] = a;
        }
      }
#pragma unroll
      for (int mt = 0; mt < 4; ++mt)
#pragma unroll
        for (int v = 0; v < 4; ++v)
          atomicAdd(&zB[(mt * 16 + quad * 4 + v) * 18 + r], accB[mt][v]);
    }

    __syncthreads();

    // ---- gates + h store (fragment-contiguous H2 layout) ----
    if (tA >= 0 && tA < kT) {
      const int par = tA & 1;
      u16* HH = hhi + (size_t)(lA * 2 + par) * BH;
      u16* HL = hlo + (size_t)(lA * 2 + par) * BH;
#pragma unroll
      for (int rp = 0; rp < 2; ++rp) {
        int p2 = tid + 512 * rp;
        int b = p2 >> 4, u = p2 & 15;
        float zi = zA[b * 66 + u] + bA[0];
        float zfg = zA[b * 66 + 16 + u] + bA[1];
        float zg = zA[b * 66 + 32 + u] + bA[2];
        float zo = zA[b * 66 + 48 + u] + bA[3];
        float cp = (tA == 0) ? 0.f : (rp ? cA1 : cA0);
        float cn = sigf(zfg) * cp + sigf(zi) * tanh_s(zg);
        float hn = sigf(zo) * tanh_s(cn);
        if (rp) cA1 = cn; else cA0 = cn;
        short hh, ll;
        split_bf16(hn, hh, ll);
        size_t off = ((size_t)(jb * 2 + (u >> 3)) * 64 + b) * 8 + (u & 7);
        HH[off] = (u16)hh;
        HL[off] = (u16)ll;
      }
    }
    if (tB < kT && tid < 256) {
      const int par = tB & 1;
      u16* HH = hhi + (size_t)par * BH;
      u16* HL = hlo + (size_t)par * BH;
      int b = tid >> 2, u2 = tid & 3;
      float zi = zB[b * 18 + u2] + bB[0];
      float zfg = zB[b * 18 + 4 + u2] + bB[1];
      float zg = zB[b * 18 + 8 + u2] + bB[2];
      float zo = zB[b * 18 + 12 + u2] + bB[3];
      float cp = (tB == 0) ? 0.f : cB0;
      float cn = sigf(zfg) * cp + sigf(zi) * tanh_s(zg);
      float hn = sigf(zo) * tanh_s(cn);
      cB0 = cn;
      short hh, ll;
      split_bf16(hn, hh, ll);
      int uglob = ub + u2;
      size_t off = ((size_t)(uglob >> 3) * 64 + b) * 8 + (uglob & 7);
      HH[off] = (u16)hh;
      HL[off] = (u16)ll;
    }

    grid.sync();
  }

  // ---- head ----
  if (g < 80) {
    int p = g * 8 + wv;
    int b = p / 10, cc = p - b * 10;
    const u16* HH = hhi + (size_t)(4 * 2 + 1) * BH;
    const u16* HL = hlo + (size_t)(4 * 2 + 1) * BH;
    float sum = 0.f;
    for (int j = lane; j < kH; j += 64) {
      size_t off = ((size_t)(j >> 3) * 64 + b) * 8 + (j & 7);
      sum += (bf2f(HH[off]) + bf2f(HL[off])) * W_head[(size_t)j * kC + cc];
    }
#pragma unroll
    for (int off = 32; off > 0; off >>= 1) sum += __shfl_down(sum, off, 64);
    if (lane == 0) out[p] = sum + b_head[cc];
  }
}

// Fallback weight-lo buffer, allocated at library load (NOT inside kernel_launch).
static u16* g_wl = nullptr;
__attribute__((constructor)) static void alloc_wl() {
  hipMalloc((void**)&g_wl, (WLA_ELEMS + WLB_ELEMS) * sizeof(u16));
}

extern "C" void kernel_launch(void* const* d_in, const int* in_sizes, int n_in,
                              void* d_out, int out_size, void* d_ws, size_t ws_size,
                              hipStream_t stream) {
  const float* x = (const float*)d_in[0];
  const float* Wx0 = (const float*)d_in[1];
  const float* Wxs = (const float*)d_in[2];
  const float* Whs = (const float*)d_in[3];
  const float* bs = (const float*)d_in[4];
  const float* W_head = (const float*)d_in[5];
  const float* b_head = (const float*)d_in[6];
  float* out = (float*)d_out;

  u16* hhi = (u16*)d_ws;
  u16* hlo = hhi + H_ELEMS;
  u16* ws_wl = hlo + H_ELEMS;
  size_t need = (2 * H_ELEMS + WLA_ELEMS + WLB_ELEMS) * sizeof(u16);
  u16 *wlA, *wlB;
  if (ws_size >= need) {
    wlA = ws_wl;
    wlB = wlA + WLA_ELEMS;
  } else {
    wlA = g_wl;
    wlB = g_wl + WLA_ELEMS;
  }

  split_wl<<<256, 512, 0, stream>>>(Wx0, Wxs, Whs, wlA, wlB);

  void* args[] = {&x, &Wx0, &Wxs, &Whs, &bs, &W_head, &b_head,
                  &out, &hhi, &hlo, &wlA, &wlB};
  hipLaunchCooperativeKernel((void*)lstm_persist, dim3(256), dim3(512), args, 0,
                             stream);
}